// Round 5
// baseline (80.033 us; speedup 1.0000x reference)
//
#include <hip/hip_runtime.h>

#define BATCH 8
#define ROWS 1536
#define KCLS 32
#define NTOT (BATCH*ROWS)        // 12288
#define ELEMS (NTOT*16)          // 196608
#define SSTRIDE 3073             // padded prefix-sum stride per batch
#define BIGF 1.0e30f

// workspace layout (float offsets)
enum : int {
  WS_Z     = 0,                          // [8][1536][16]
  WS_X     = WS_Z + NTOT*16,             // [8][1536]
  WS_XS    = WS_X + NTOT,                // [8][1536]
  WS_S     = WS_XS + NTOT,               // [8][3073] padded
  WS_DESC  = WS_S + BATCH*SSTRIDE,       // [8][1536] int
  WS_ASCP  = WS_DESC + NTOT,             // [4][12288] int
  WS_DSCP  = WS_ASCP + 4*NTOT,           // [4][12288] int
  WS_GPART = WS_DSCP + 4*NTOT,           // [8][8][1536] (k8a) / [8][24][512] (cpart)
  WS_LOSSP = WS_GPART + BATCH*8*ROWS,    // [192]
};
#define WS_CPART WS_GPART   // disjoint lifetimes: cpart k1->k345, gpart k8a->k8b

// LDS weight layout (float offsets)
#define LW1  0
#define LB1  512
#define LW2  544
#define LB2  2592
#define LMW  2656
#define LMB  3680
#define LDW1 3696
#define LDB1 4208
#define LDW2 4240
#define LDB2 4752
#define LTOT 4768

// activation features in LDS [feature][64 lanes]
#define AX   0
#define AH1  16
#define AH2  48
#define AZ   112
#define AR1  128
#define AREC 144
#define ATOT 160

// One MLP layer: act[OUT] = (RELU?)(act[IN] @ W + b). Rolled i-loop (I$-small);
// accumulators are compile-time-indexed registers; weights read as wave-uniform
// float4 broadcast; activations per-lane stride-1 (2 lanes/bank = free).
template<int IN_BASE, int IN_N, int OUT_BASE, int OUT_N, int WOFF, int BOFF, bool RELU>
__device__ __forceinline__ void mlp_layer(float* __restrict__ act,
                                          const float* __restrict__ wsh,
                                          int tid)
{
#pragma unroll
  for (int oc = 0; oc < OUT_N/16; ++oc) {
    float acc[16];
    {
      const float4* bp = reinterpret_cast<const float4*>(&wsh[BOFF + oc*16]);
      float4 b0 = bp[0], b1 = bp[1], b2 = bp[2], b3 = bp[3];
      acc[0]=b0.x;  acc[1]=b0.y;  acc[2]=b0.z;  acc[3]=b0.w;
      acc[4]=b1.x;  acc[5]=b1.y;  acc[6]=b1.z;  acc[7]=b1.w;
      acc[8]=b2.x;  acc[9]=b2.y;  acc[10]=b2.z; acc[11]=b2.w;
      acc[12]=b3.x; acc[13]=b3.y; acc[14]=b3.z; acc[15]=b3.w;
    }
#pragma unroll 2
    for (int i = 0; i < IN_N; ++i) {
      const float s = act[(IN_BASE + i)*64 + tid];
      const float4* wp = reinterpret_cast<const float4*>(&wsh[WOFF + i*OUT_N + oc*16]);
      float4 w0 = wp[0], w1 = wp[1], w2 = wp[2], w3 = wp[3];
      acc[0]  = fmaf(s, w0.x, acc[0]);  acc[1]  = fmaf(s, w0.y, acc[1]);
      acc[2]  = fmaf(s, w0.z, acc[2]);  acc[3]  = fmaf(s, w0.w, acc[3]);
      acc[4]  = fmaf(s, w1.x, acc[4]);  acc[5]  = fmaf(s, w1.y, acc[5]);
      acc[6]  = fmaf(s, w1.z, acc[6]);  acc[7]  = fmaf(s, w1.w, acc[7]);
      acc[8]  = fmaf(s, w2.x, acc[8]);  acc[9]  = fmaf(s, w2.y, acc[9]);
      acc[10] = fmaf(s, w2.z, acc[10]); acc[11] = fmaf(s, w2.w, acc[11]);
      acc[12] = fmaf(s, w3.x, acc[12]); acc[13] = fmaf(s, w3.y, acc[13]);
      acc[14] = fmaf(s, w3.z, acc[14]); acc[15] = fmaf(s, w3.w, acc[15]);
    }
#pragma unroll
    for (int j = 0; j < 16; ++j) {
      float v = RELU ? fmaxf(acc[j], 0.f) : acc[j];
      act[(OUT_BASE + oc*16 + j)*64 + tid] = v;
    }
  }
}

// ---- K1: autoencoder + z + loss partials + fused center partials ----
__global__ __launch_bounds__(64, 2) void k1_ae(
    const float* __restrict__ table,
    const float* __restrict__ w1, const float* __restrict__ b1,
    const float* __restrict__ w2, const float* __restrict__ b2,
    const float* __restrict__ mw, const float* __restrict__ mb,
    const float* __restrict__ dw1, const float* __restrict__ db1,
    const float* __restrict__ dw2, const float* __restrict__ db2,
    const int* __restrict__ labels,
    float* __restrict__ ws)
{
  const int tid = threadIdx.x;
  const int blk = blockIdx.x;            // 0..191
  const int row = blk * 64 + tid;        // global row
  const int b   = blk / 24;              // batch
  const int ch  = blk % 24;              // 64-row chunk within batch

  __shared__ float wsh[LTOT];
  __shared__ float act[ATOT * 64];
  __shared__ int   lbl[64];

  // stage weights (float4, coalesced)
  {
    float4* d4 = reinterpret_cast<float4*>(wsh);
#define CPY(off, src, nf4) \
    { const float4* p = reinterpret_cast<const float4*>(src); \
      for (int t = tid; t < (nf4); t += 64) d4[(off)/4 + t] = p[t]; }
    CPY(LW1,  w1,  128) CPY(LB1,  b1,  8)  CPY(LW2,  w2,  512)
    CPY(LB2,  b2,  16)  CPY(LMW,  mw,  256) CPY(LMB,  mb,  4)
    CPY(LDW1, dw1, 128) CPY(LDB1, db1, 8)  CPY(LDW2, dw2, 128)
    CPY(LDB2, db2, 4)
#undef CPY
    lbl[tid] = labels[ch * 64 + tid];
  }
  __syncthreads();

  // load x -> act[feature][tid]
  {
    const float4* tp = reinterpret_cast<const float4*>(table + row * 16);
    float4 a0 = tp[0], a1 = tp[1], a2 = tp[2], a3 = tp[3];
    act[(AX+0)*64+tid]=a0.x;  act[(AX+1)*64+tid]=a0.y;
    act[(AX+2)*64+tid]=a0.z;  act[(AX+3)*64+tid]=a0.w;
    act[(AX+4)*64+tid]=a1.x;  act[(AX+5)*64+tid]=a1.y;
    act[(AX+6)*64+tid]=a1.z;  act[(AX+7)*64+tid]=a1.w;
    act[(AX+8)*64+tid]=a2.x;  act[(AX+9)*64+tid]=a2.y;
    act[(AX+10)*64+tid]=a2.z; act[(AX+11)*64+tid]=a2.w;
    act[(AX+12)*64+tid]=a3.x; act[(AX+13)*64+tid]=a3.y;
    act[(AX+14)*64+tid]=a3.z; act[(AX+15)*64+tid]=a3.w;
  }

  // 5-layer MLP, all within this thread's LDS column (no barriers needed)
  mlp_layer<AX,  16, AH1, 32, LW1,  LB1,  true >(act, wsh, tid);
  mlp_layer<AH1, 32, AH2, 64, LW2,  LB2,  true >(act, wsh, tid);
  mlp_layer<AH2, 64, AZ,  16, LMW,  LMB,  false>(act, wsh, tid);
  mlp_layer<AZ,  16, AR1, 32, LDW1, LDB1, true >(act, wsh, tid);
  mlp_layer<AR1, 32, AREC,16, LDW2, LDB2, true >(act, wsh, tid);

  // z -> global (float4)
  {
    float zz[16];
#pragma unroll
    for (int j = 0; j < 16; ++j) zz[j] = act[(AZ+j)*64 + tid];
    float4* zp = reinterpret_cast<float4*>(ws + WS_Z + row * 16);
    zp[0] = make_float4(zz[0],  zz[1],  zz[2],  zz[3]);
    zp[1] = make_float4(zz[4],  zz[5],  zz[6],  zz[7]);
    zp[2] = make_float4(zz[8],  zz[9],  zz[10], zz[11]);
    zp[3] = make_float4(zz[12], zz[13], zz[14], zz[15]);
  }

  // loss partial
  float ls = 0.f;
#pragma unroll
  for (int j = 0; j < 16; ++j) {
    float d = act[(AREC+j)*64 + tid] - act[(AX+j)*64 + tid];
    ls = fmaf(d, d, ls);
  }
  for (int off = 32; off > 0; off >>= 1) ls += __shfl_down(ls, off);
  if (tid == 0) ws[WS_LOSSP + blk] = ls;

  // fused center partials over this 64-row chunk (reads other lanes' z)
  __syncthreads();
  float acc[8] = {0.f,0.f,0.f,0.f,0.f,0.f,0.f,0.f};
  for (int rr = 0; rr < 64; ++rr) {
    const int lb = lbl[rr];
#pragma unroll
    for (int p = 0; p < 8; ++p) {
      const int idx = tid*8 + p;
      acc[p] += (lb == (idx >> 4)) ? act[(AZ + (idx & 15))*64 + rr] : 0.f;
    }
  }
#pragma unroll
  for (int p = 0; p < 8; ++p)
    ws[WS_CPART + (b*24 + ch)*512 + tid*8 + p] = acc[p];
}

// ---- K345: centers finalize + loss + d2 + normalizations + scores + x ------
__global__ __launch_bounds__(256) void k345(const int* __restrict__ labels,
                                            float* __restrict__ ws,
                                            float* __restrict__ out)
{
  const int b = blockIdx.x;
  const int tid = threadIdx.x;
  __shared__ int cnt[KCLS];
  __shared__ float cent[512];
  __shared__ float rmn[256], rmx[256];
  __shared__ int lbl_l[ROWS];

  // loss reduction (all blocks compute, block 0 writes)
  rmn[tid] = (tid < 192) ? ws[WS_LOSSP + tid] : 0.f;
  if (tid < KCLS) cnt[tid] = 0;
  __syncthreads();
  for (int off = 128; off > 0; off >>= 1) {
    if (tid < off) rmn[tid] += rmn[tid + off];
    __syncthreads();
  }
  if (b == 0 && tid == 0) out[3*NTOT] = rmn[0] / (float)ELEMS;

#pragma unroll
  for (int c = 0; c < 6; ++c) {
    int lb = labels[c*256 + tid];
    lbl_l[c*256 + tid] = lb;
    atomicAdd(&cnt[lb], 1);
  }
  __syncthreads();
#pragma unroll
  for (int e = tid; e < 512; e += 256) {
    float s = 0.f;
#pragma unroll
    for (int c = 0; c < 24; ++c) s += ws[WS_CPART + (b*24 + c)*512 + e];
    const int cn = cnt[e >> 4] > 1 ? cnt[e >> 4] : 1;
    cent[e] = s / (float)cn;
  }
  __syncthreads();

  // d2 per row (6 rows/thread), block min/max
  float d2v[6];
  float tmn = 3.0e38f, tmx = -3.0e38f;
#pragma unroll
  for (int c = 0; c < 6; ++c) {
    const int r = c*256 + tid;
    const int lb = lbl_l[r];
    const float4* zp = reinterpret_cast<const float4*>(ws + WS_Z + (b*ROWS + r)*16);
    const float4* cp = reinterpret_cast<const float4*>(&cent[lb*16]);
    float s = 0.f;
#pragma unroll
    for (int q = 0; q < 4; ++q) {
      float4 zv = zp[q], cv = cp[q];
      float d0 = zv.x - cv.x, d1 = zv.y - cv.y, d2_ = zv.z - cv.z, d3 = zv.w - cv.w;
      s += d0*d0 + d1*d1 + d2_*d2_ + d3*d3;
    }
    d2v[c] = s / 16.f;
    tmn = fminf(tmn, d2v[c]); tmx = fmaxf(tmx, d2v[c]);
  }
  rmn[tid] = tmn; rmx[tid] = tmx;
  __syncthreads();
  for (int off = 128; off > 0; off >>= 1) {
    if (tid < off) {
      rmn[tid] = fminf(rmn[tid], rmn[tid + off]);
      rmx[tid] = fmaxf(rmx[tid], rmx[tid + off]);
    }
    __syncthreads();
  }
  const float mn = rmn[0], mx = rmx[0];
  __syncthreads();

  float sv[6];
  tmn = 3.0e38f; tmx = -3.0e38f;
#pragma unroll
  for (int c = 0; c < 6; ++c) {
    const int r = c*256 + tid;
    float sc = (d2v[c] - mn) / (mx - mn) + (float)lbl_l[r];
    sv[c] = sc;
    out[2*NTOT + b*ROWS + r] = sc;
    tmn = fminf(tmn, sc); tmx = fmaxf(tmx, sc);
  }
  rmn[tid] = tmn; rmx[tid] = tmx;
  __syncthreads();
  for (int off = 128; off > 0; off >>= 1) {
    if (tid < off) {
      rmn[tid] = fminf(rmn[tid], rmn[tid + off]);
      rmx[tid] = fmaxf(rmx[tid], rmx[tid + off]);
    }
    __syncthreads();
  }
  const float smn = rmn[0], smx = rmx[0];
#pragma unroll
  for (int c = 0; c < 6; ++c) {
    const int r = c*256 + tid;
    float scl = (sv[c] - smn) / (smx - smn) * 8.0f;
    ws[WS_X + b*ROWS + r] = scl / 0.01f;
  }
}

// ---------------- K6: partial stable rank counts (192 blocks) ----------------
__global__ __launch_bounds__(256) void k6_count(float* __restrict__ ws,
                                                const float* __restrict__ out)
{
  const int bi = blockIdx.x;
  const int jb = bi & 3, rb = (bi >> 2) % 6, b = bi / 24;
  const int tid = threadIdx.x;
  __shared__ float4 sld[96], xld[96];
  {
    float* sf = reinterpret_cast<float*>(sld);
    float* xf = reinterpret_cast<float*>(xld);
    const int base = b*ROWS + jb*384;
    sf[tid] = out[2*NTOT + base + tid];
    xf[tid] = ws[WS_X + base + tid];
    if (tid < 128) {
      sf[256 + tid] = out[2*NTOT + base + 256 + tid];
      xf[256 + tid] = ws[WS_X + base + 256 + tid];
    }
  }
  __syncthreads();
  const int r = rb*256 + tid;
  const float si = out[2*NTOT + b*ROWS + r];
  const float xi = ws[WS_X + b*ROWS + r];
  int asc = 0, dsc = 0;
  const int j0 = jb*384;
#pragma unroll 4
  for (int kk = 0; kk < 96; ++kk) {
    const float4 s4 = sld[kk];
    const float4 x4 = xld[kk];
    const int j = j0 + kk*4;
    asc += (s4.x < si || (s4.x == si && j   < r)) ? 1 : 0;
    asc += (s4.y < si || (s4.y == si && j+1 < r)) ? 1 : 0;
    asc += (s4.z < si || (s4.z == si && j+2 < r)) ? 1 : 0;
    asc += (s4.w < si || (s4.w == si && j+3 < r)) ? 1 : 0;
    dsc += (x4.x > xi || (x4.x == xi && j   < r)) ? 1 : 0;
    dsc += (x4.y > xi || (x4.y == xi && j+1 < r)) ? 1 : 0;
    dsc += (x4.z > xi || (x4.z == xi && j+2 < r)) ? 1 : 0;
    dsc += (x4.w > xi || (x4.w == xi && j+3 < r)) ? 1 : 0;
  }
  int* wsi = reinterpret_cast<int*>(ws);
  wsi[WS_ASCP + jb*NTOT + b*ROWS + r] = asc;
  wsi[WS_DSCP + jb*NTOT + b*ROWS + r] = dsc;
}

// ------- K67: finalize counts -> rank_idx, scatter xs, prefix-sum S ---------
__global__ __launch_bounds__(256) void k67(const int* __restrict__ bsp,
                                           float* __restrict__ ws,
                                           float* __restrict__ out)
{
  const int b = blockIdx.x, tid = threadIdx.x;
  __shared__ float xs_l[ROWS];
  __shared__ float ts[256];
  const int* wsi = reinterpret_cast<const int*>(ws);
  int* wsw = reinterpret_cast<int*>(ws);
  const int BS = *bsp;
#pragma unroll
  for (int c = 0; c < 6; ++c) {
    const int r = c*256 + tid;
    const int idx = b*ROWS + r;
    int asc = 0, dsc = 0;
#pragma unroll
    for (int jb = 0; jb < 4; ++jb) {
      asc += wsi[WS_ASCP + jb*NTOT + idx];
      dsc += wsi[WS_DSCP + jb*NTOT + idx];
    }
    out[NTOT + idx] = (float)(asc / BS + 1);
    wsw[WS_DESC + idx] = dsc;
    xs_l[dsc] = ws[WS_X + idx];
  }
  __syncthreads();
  const int base = tid * 6;
  float y[6], sum = 0.f;
#pragma unroll
  for (int u = 0; u < 6; ++u) {
    ws[WS_XS + b*ROWS + base + u] = xs_l[base + u];
    y[u] = (float)(ROWS - (base + u)) - xs_l[base + u];
    sum += y[u];
  }
  ts[tid] = sum;
  __syncthreads();
  for (int off = 1; off < 256; off <<= 1) {
    float v = ts[tid];
    if (tid >= off) v += ts[tid - off];
    __syncthreads();
    ts[tid] = v;
    __syncthreads();
  }
  float run = tid ? ts[tid - 1] : 0.f;
  float* S = ws + WS_S + b*SSTRIDE;
#pragma unroll
  for (int u = 0; u < 6; ++u) { S[base + u] = run; run += y[u]; }
  if (tid == 255) S[ROWS] = run;
#pragma unroll
  for (int u = 0; u < 6; ++u) S[ROWS + 1 + tid*6 + u] = BIGF;
}

// ---------------- K8a: chunk-partial minima of segment averages --------------
__global__ __launch_bounds__(256) void k8a(float* __restrict__ ws)
{
  const int bi = blockIdx.x;
  const int c = bi & 7, ib = (bi >> 3) % 6, b = bi / 48;
  const int tid = threadIdx.x;
  __shared__ float Sseg[448];
  __shared__ float invl[192];
  const float* S = ws + WS_S + b*SSTRIDE;
  const int ibase = ib*256;
  const int segbase = ibase + c*192 + 1;
  Sseg[tid] = S[segbase + tid];
  if (tid < 192) {
    Sseg[256 + tid] = S[segbase + 256 + tid];
    invl[tid] = 1.0f / (float)(c*192 + tid + 1);
  }
  __syncthreads();
  const int i = ibase + tid;
  const float Si = S[i];
  float gm = 3.0e38f;
#pragma unroll 8
  for (int k = 0; k < 192; ++k)
    gm = fminf(gm, (Sseg[tid + k] - Si) * invl[k]);
  ws[WS_GPART + (b*8 + c)*ROWS + i] = gm;
}

// --------- K8b: reduce partials, prefix-max (isotonic), final ranks ----------
__global__ __launch_bounds__(768) void k8b(float* __restrict__ ws,
                                           float* __restrict__ out)
{
  const int b = blockIdx.x, tid = threadIdx.x;
  __shared__ float g[ROWS];
  __shared__ float pm[768];
  for (int t = tid; t < ROWS; t += 768) {
    float gm = 3.0e38f;
#pragma unroll
    for (int c = 0; c < 8; ++c)
      gm = fminf(gm, ws[WS_GPART + (b*8 + c)*ROWS + t]);
    g[t] = gm;
  }
  __syncthreads();
  const float a = g[2*tid], cc = g[2*tid + 1];
  pm[tid] = fmaxf(a, cc);
  __syncthreads();
  for (int off = 1; off < 768; off <<= 1) {
    float v = pm[tid];
    if (tid >= off) v = fmaxf(v, pm[tid - off]);
    __syncthreads();
    pm[tid] = v;
    __syncthreads();
  }
  const float excl = tid ? pm[tid - 1] : -3.0e38f;
  const float i0 = fmaxf(excl, a);
  const float i1 = fmaxf(i0, cc);
  g[2*tid] = i0; g[2*tid + 1] = i1;
  __syncthreads();
  const float* xs = ws + WS_XS + b*ROWS;
  const int* desc = reinterpret_cast<const int*>(ws) + WS_DESC + b*ROWS;
  for (int t = tid; t < ROWS; t += 768) {
    const int dr = desc[t];
    out[b*ROWS + t] = xs[dr] + g[dr];
  }
}

extern "C" void kernel_launch(void* const* d_in, const int* in_sizes, int n_in,
                              void* d_out, int out_size, void* d_ws, size_t ws_size,
                              hipStream_t stream) {
  const float* table = (const float*)d_in[0];
  const float* w1  = (const float*)d_in[1];
  const float* b1  = (const float*)d_in[2];
  const float* w2  = (const float*)d_in[3];
  const float* b2  = (const float*)d_in[4];
  const float* mw  = (const float*)d_in[5];
  const float* mb  = (const float*)d_in[6];
  const float* dw1 = (const float*)d_in[7];
  const float* db1 = (const float*)d_in[8];
  const float* dw2 = (const float*)d_in[9];
  const float* db2 = (const float*)d_in[10];
  const int* labels = (const int*)d_in[11];
  const int* bsp    = (const int*)d_in[12];
  float* out = (float*)d_out;
  float* ws  = (float*)d_ws;

  k1_ae<<<192, 64, 0, stream>>>(table, w1, b1, w2, b2, mw, mb, dw1, db1, dw2, db2, labels, ws);
  k345<<<8, 256, 0, stream>>>(labels, ws, out);
  k6_count<<<192, 256, 0, stream>>>(ws, out);
  k67<<<8, 256, 0, stream>>>(bsp, ws, out);
  k8a<<<384, 256, 0, stream>>>(ws);
  k8b<<<8, 768, 0, stream>>>(ws, out);
}

// Round 6
// 62.714 us; speedup vs baseline: 1.2762x; 1.2762x over previous
//
#include <hip/hip_runtime.h>

#define BATCH 8
#define ROWS 1536
#define KCLS 32
#define NTOT (BATCH*ROWS)        // 12288
#define ELEMS (NTOT*16)          // 196608
#define SSTRIDE 3073             // padded prefix-sum stride per batch
#define BIGF 1.0e30f

// workspace layout (float offsets)
enum : int {
  WS_Z     = 0,                          // [8][1536][16]
  WS_X     = WS_Z + NTOT*16,             // [8][1536]
  WS_XS    = WS_X + NTOT,                // [8][1536]
  WS_S     = WS_XS + NTOT,               // [8][3073] padded
  WS_DESC  = WS_S + BATCH*SSTRIDE,       // [8][1536] int
  WS_ASCP  = WS_DESC + NTOT,             // [4][12288] int
  WS_DSCP  = WS_ASCP + 4*NTOT,           // [4][12288] int
  WS_GPART = WS_DSCP + 4*NTOT,           // [8][8][1536] (k8a) / [8][24][512] (cpart)
  WS_LOSSP = WS_GPART + BATCH*8*ROWS,    // [192]
};
#define WS_CPART WS_GPART   // disjoint lifetimes: cpart k1->k345, gpart k8a->k8b

// LDS weight layout (float offsets)
#define LW1  0
#define LB1  512
#define LW2  544
#define LB2  2592
#define LMW  2656
#define LMB  3680
#define LDW1 3696
#define LDB1 4208
#define LDW2 4240
#define LDB2 4752
#define LTOT 4768

// activation features per row (float offsets, all multiples of 4)
#define AX   0
#define AH1  16
#define AH2  48
#define AZ   112
#define AR1  128
#define AREC 144
#define ATOT 160
#define ASTRIDE 164   // row stride in floats (41 float4s, 16B-aligned)

// One layer, feature-split across 4 waves: wave w computes outputs
// [w*OUT_PW, (w+1)*OUT_PW) for its lane's row. act is [row][ASTRIDE].
// Weights read wave-uniform (LDS broadcast); act read as per-lane float4.
template<int IN_BASE, int IN_N, int OUT_BASE, int OUT_PW, int OUT_TOT,
         int WOFF, int BOFF, bool RELU>
__device__ __forceinline__ void layerw(float* __restrict__ act,
                                       const float* __restrict__ wsh,
                                       int lrow, int wav)
{
  const int o0 = wav * OUT_PW;
  float acc[OUT_PW];
#pragma unroll
  for (int j = 0; j < OUT_PW; ++j) acc[j] = wsh[BOFF + o0 + j];

  const float4* arow = reinterpret_cast<const float4*>(&act[lrow*ASTRIDE + IN_BASE]);
#pragma unroll 2
  for (int i4 = 0; i4 < IN_N/4; ++i4) {
    float4 sv = arow[i4];
    float svx[4];
    svx[0] = sv.x; svx[1] = sv.y; svx[2] = sv.z; svx[3] = sv.w;
#pragma unroll
    for (int u = 0; u < 4; ++u) {
      const float s = svx[u];
      const float4* wp =
        reinterpret_cast<const float4*>(&wsh[WOFF + (i4*4 + u)*OUT_TOT + o0]);
#pragma unroll
      for (int q = 0; q < OUT_PW/4; ++q) {
        float4 w = wp[q];
        acc[q*4+0] = fmaf(s, w.x, acc[q*4+0]);
        acc[q*4+1] = fmaf(s, w.y, acc[q*4+1]);
        acc[q*4+2] = fmaf(s, w.z, acc[q*4+2]);
        acc[q*4+3] = fmaf(s, w.w, acc[q*4+3]);
      }
    }
  }
  float4* orow = reinterpret_cast<float4*>(&act[lrow*ASTRIDE + OUT_BASE + o0]);
#pragma unroll
  for (int q = 0; q < OUT_PW/4; ++q) {
    float4 v;
    v.x = RELU ? fmaxf(acc[q*4+0], 0.f) : acc[q*4+0];
    v.y = RELU ? fmaxf(acc[q*4+1], 0.f) : acc[q*4+1];
    v.z = RELU ? fmaxf(acc[q*4+2], 0.f) : acc[q*4+2];
    v.w = RELU ? fmaxf(acc[q*4+3], 0.f) : acc[q*4+3];
    orow[q] = v;
  }
}

// ---- K1: autoencoder + z + loss partials + fused center partials ----
// 256 threads = 4 waves; 64 rows/block; features split across waves.
__global__ __launch_bounds__(256, 2) void k1_ae(
    const float* __restrict__ table,
    const float* __restrict__ w1, const float* __restrict__ b1,
    const float* __restrict__ w2, const float* __restrict__ b2,
    const float* __restrict__ mw, const float* __restrict__ mb,
    const float* __restrict__ dw1, const float* __restrict__ db1,
    const float* __restrict__ dw2, const float* __restrict__ db2,
    const int* __restrict__ labels,
    float* __restrict__ ws)
{
  const int tid  = threadIdx.x;
  const int lrow = tid & 63;             // lane's row within block
  const int wav  = tid >> 6;             // wave id 0..3 (feature split)
  const int blk  = blockIdx.x;           // 0..191
  const int b    = blk / 24;             // batch
  const int ch   = blk % 24;             // 64-row chunk within batch

  __shared__ float wsh[LTOT];            // 19 KB weights
  __shared__ float act[64 * ASTRIDE];    // 42 KB activations [row][feat]
  __shared__ int   lbl[64];
  __shared__ float lred[4];

  // stage weights (float4, coalesced, 256 threads)
  {
    float4* d4 = reinterpret_cast<float4*>(wsh);
#define CPY(off, src, nf4) \
    { const float4* p = reinterpret_cast<const float4*>(src); \
      for (int t = tid; t < (nf4); t += 256) d4[(off)/4 + t] = p[t]; }
    CPY(LW1,  w1,  128) CPY(LB1,  b1,  8)  CPY(LW2,  w2,  512)
    CPY(LB2,  b2,  16)  CPY(LMW,  mw,  256) CPY(LMB,  mb,  4)
    CPY(LDW1, dw1, 128) CPY(LDB1, db1, 8)  CPY(LDW2, dw2, 128)
    CPY(LDB2, db2, 4)
#undef CPY
    if (tid < 64) lbl[tid] = labels[ch * 64 + tid];
    // load x: thread t loads global float4 #t of this block's 64 rows
    const float4* tp = reinterpret_cast<const float4*>(table) + blk*256 + tid;
    float4* a4 = reinterpret_cast<float4*>(act);
    a4[(tid >> 2) * (ASTRIDE/4) + (tid & 3)] = *tp;
  }
  __syncthreads();

  layerw<AX,  16, AH1,  8, 32, LW1,  LB1,  true >(act, wsh, lrow, wav);
  __syncthreads();
  layerw<AH1, 32, AH2, 16, 64, LW2,  LB2,  true >(act, wsh, lrow, wav);
  __syncthreads();
  layerw<AH2, 64, AZ,   4, 16, LMW,  LMB,  false>(act, wsh, lrow, wav);
  __syncthreads();

  // z -> global (coalesced: thread t writes global float4 #t)
  {
    const float4* a4 = reinterpret_cast<const float4*>(act);
    float4 zv = a4[(tid >> 2) * (ASTRIDE/4) + (AZ/4) + (tid & 3)];
    reinterpret_cast<float4*>(ws + WS_Z)[blk*256 + tid] = zv;
  }

  layerw<AZ,  16, AR1,  8, 32, LDW1, LDB1, true >(act, wsh, lrow, wav);
  __syncthreads();
  layerw<AR1, 32, AREC, 4, 16, LDW2, LDB2, true >(act, wsh, lrow, wav);
  __syncthreads();

  // loss: wave w sums its 4 rec features vs x for its lane's row
  {
    const float4* arow4 = reinterpret_cast<const float4*>(&act[lrow*ASTRIDE]);
    float4 rc = arow4[AREC/4 + wav];
    float4 xv = arow4[AX/4 + wav];
    float d0 = rc.x - xv.x, d1 = rc.y - xv.y, d2 = rc.z - xv.z, d3 = rc.w - xv.w;
    float ls = d0*d0 + d1*d1 + d2*d2 + d3*d3;
    for (int off = 32; off > 0; off >>= 1) ls += __shfl_down(ls, off);
    if (lrow == 0) lred[wav] = ls;
    __syncthreads();
    if (tid == 0) ws[WS_LOSSP + blk] = (lred[0] + lred[1]) + (lred[2] + lred[3]);
  }

  // fused center partials: 512 outputs, 2 per thread
  {
    float a0 = 0.f, a1 = 0.f;
    const int d0 = tid & 15,        k0 = tid >> 4;        // e = tid
    const int k1c = k0 + 16;                              // e = tid + 256
    for (int rr = 0; rr < 64; ++rr) {
      const int lb = lbl[rr];
      const float zv = act[rr*ASTRIDE + AZ + d0];
      a0 += (lb == k0)  ? zv : 0.f;
      a1 += (lb == k1c) ? zv : 0.f;
    }
    ws[WS_CPART + (b*24 + ch)*512 + tid]       = a0;
    ws[WS_CPART + (b*24 + ch)*512 + 256 + tid] = a1;
  }
}

// ---- K345: centers finalize + loss + d2 + normalizations + scores + x ------
__global__ __launch_bounds__(256) void k345(const int* __restrict__ labels,
                                            float* __restrict__ ws,
                                            float* __restrict__ out)
{
  const int b = blockIdx.x;
  const int tid = threadIdx.x;
  __shared__ int cnt[KCLS];
  __shared__ float cent[512];
  __shared__ float rmn[256], rmx[256];
  __shared__ int lbl_l[ROWS];

  // loss reduction (all blocks compute, block 0 writes)
  rmn[tid] = (tid < 192) ? ws[WS_LOSSP + tid] : 0.f;
  if (tid < KCLS) cnt[tid] = 0;
  __syncthreads();
  for (int off = 128; off > 0; off >>= 1) {
    if (tid < off) rmn[tid] += rmn[tid + off];
    __syncthreads();
  }
  if (b == 0 && tid == 0) out[3*NTOT] = rmn[0] / (float)ELEMS;

#pragma unroll
  for (int c = 0; c < 6; ++c) {
    int lb = labels[c*256 + tid];
    lbl_l[c*256 + tid] = lb;
    atomicAdd(&cnt[lb], 1);
  }
  __syncthreads();
#pragma unroll
  for (int e = tid; e < 512; e += 256) {
    float s = 0.f;
#pragma unroll
    for (int c = 0; c < 24; ++c) s += ws[WS_CPART + (b*24 + c)*512 + e];
    const int cn = cnt[e >> 4] > 1 ? cnt[e >> 4] : 1;
    cent[e] = s / (float)cn;
  }
  __syncthreads();

  // d2 per row (6 rows/thread), block min/max
  float d2v[6];
  float tmn = 3.0e38f, tmx = -3.0e38f;
#pragma unroll
  for (int c = 0; c < 6; ++c) {
    const int r = c*256 + tid;
    const int lb = lbl_l[r];
    const float4* zp = reinterpret_cast<const float4*>(ws + WS_Z + (b*ROWS + r)*16);
    const float4* cp = reinterpret_cast<const float4*>(&cent[lb*16]);
    float s = 0.f;
#pragma unroll
    for (int q = 0; q < 4; ++q) {
      float4 zv = zp[q], cv = cp[q];
      float d0 = zv.x - cv.x, d1 = zv.y - cv.y, d2_ = zv.z - cv.z, d3 = zv.w - cv.w;
      s += d0*d0 + d1*d1 + d2_*d2_ + d3*d3;
    }
    d2v[c] = s / 16.f;
    tmn = fminf(tmn, d2v[c]); tmx = fmaxf(tmx, d2v[c]);
  }
  rmn[tid] = tmn; rmx[tid] = tmx;
  __syncthreads();
  for (int off = 128; off > 0; off >>= 1) {
    if (tid < off) {
      rmn[tid] = fminf(rmn[tid], rmn[tid + off]);
      rmx[tid] = fmaxf(rmx[tid], rmx[tid + off]);
    }
    __syncthreads();
  }
  const float mn = rmn[0], mx = rmx[0];
  __syncthreads();

  float sv[6];
  tmn = 3.0e38f; tmx = -3.0e38f;
#pragma unroll
  for (int c = 0; c < 6; ++c) {
    const int r = c*256 + tid;
    float sc = (d2v[c] - mn) / (mx - mn) + (float)lbl_l[r];
    sv[c] = sc;
    out[2*NTOT + b*ROWS + r] = sc;
    tmn = fminf(tmn, sc); tmx = fmaxf(tmx, sc);
  }
  rmn[tid] = tmn; rmx[tid] = tmx;
  __syncthreads();
  for (int off = 128; off > 0; off >>= 1) {
    if (tid < off) {
      rmn[tid] = fminf(rmn[tid], rmn[tid + off]);
      rmx[tid] = fmaxf(rmx[tid], rmx[tid + off]);
    }
    __syncthreads();
  }
  const float smn = rmn[0], smx = rmx[0];
#pragma unroll
  for (int c = 0; c < 6; ++c) {
    const int r = c*256 + tid;
    float scl = (sv[c] - smn) / (smx - smn) * 8.0f;
    ws[WS_X + b*ROWS + r] = scl / 0.01f;
  }
}

// ---------------- K6: partial stable rank counts (192 blocks) ----------------
__global__ __launch_bounds__(256) void k6_count(float* __restrict__ ws,
                                                const float* __restrict__ out)
{
  const int bi = blockIdx.x;
  const int jb = bi & 3, rb = (bi >> 2) % 6, b = bi / 24;
  const int tid = threadIdx.x;
  __shared__ float4 sld[96], xld[96];
  {
    float* sf = reinterpret_cast<float*>(sld);
    float* xf = reinterpret_cast<float*>(xld);
    const int base = b*ROWS + jb*384;
    sf[tid] = out[2*NTOT + base + tid];
    xf[tid] = ws[WS_X + base + tid];
    if (tid < 128) {
      sf[256 + tid] = out[2*NTOT + base + 256 + tid];
      xf[256 + tid] = ws[WS_X + base + 256 + tid];
    }
  }
  __syncthreads();
  const int r = rb*256 + tid;
  const float si = out[2*NTOT + b*ROWS + r];
  const float xi = ws[WS_X + b*ROWS + r];
  int asc = 0, dsc = 0;
  const int j0 = jb*384;
#pragma unroll 4
  for (int kk = 0; kk < 96; ++kk) {
    const float4 s4 = sld[kk];
    const float4 x4 = xld[kk];
    const int j = j0 + kk*4;
    asc += (s4.x < si || (s4.x == si && j   < r)) ? 1 : 0;
    asc += (s4.y < si || (s4.y == si && j+1 < r)) ? 1 : 0;
    asc += (s4.z < si || (s4.z == si && j+2 < r)) ? 1 : 0;
    asc += (s4.w < si || (s4.w == si && j+3 < r)) ? 1 : 0;
    dsc += (x4.x > xi || (x4.x == xi && j   < r)) ? 1 : 0;
    dsc += (x4.y > xi || (x4.y == xi && j+1 < r)) ? 1 : 0;
    dsc += (x4.z > xi || (x4.z == xi && j+2 < r)) ? 1 : 0;
    dsc += (x4.w > xi || (x4.w == xi && j+3 < r)) ? 1 : 0;
  }
  int* wsi = reinterpret_cast<int*>(ws);
  wsi[WS_ASCP + jb*NTOT + b*ROWS + r] = asc;
  wsi[WS_DSCP + jb*NTOT + b*ROWS + r] = dsc;
}

// ------- K67: finalize counts -> rank_idx, scatter xs, prefix-sum S ---------
__global__ __launch_bounds__(256) void k67(const int* __restrict__ bsp,
                                           float* __restrict__ ws,
                                           float* __restrict__ out)
{
  const int b = blockIdx.x, tid = threadIdx.x;
  __shared__ float xs_l[ROWS];
  __shared__ float ts[256];
  const int* wsi = reinterpret_cast<const int*>(ws);
  int* wsw = reinterpret_cast<int*>(ws);
  const int BS = *bsp;
#pragma unroll
  for (int c = 0; c < 6; ++c) {
    const int r = c*256 + tid;
    const int idx = b*ROWS + r;
    int asc = 0, dsc = 0;
#pragma unroll
    for (int jb = 0; jb < 4; ++jb) {
      asc += wsi[WS_ASCP + jb*NTOT + idx];
      dsc += wsi[WS_DSCP + jb*NTOT + idx];
    }
    out[NTOT + idx] = (float)(asc / BS + 1);
    wsw[WS_DESC + idx] = dsc;
    xs_l[dsc] = ws[WS_X + idx];
  }
  __syncthreads();
  const int base = tid * 6;
  float y[6], sum = 0.f;
#pragma unroll
  for (int u = 0; u < 6; ++u) {
    ws[WS_XS + b*ROWS + base + u] = xs_l[base + u];
    y[u] = (float)(ROWS - (base + u)) - xs_l[base + u];
    sum += y[u];
  }
  ts[tid] = sum;
  __syncthreads();
  for (int off = 1; off < 256; off <<= 1) {
    float v = ts[tid];
    if (tid >= off) v += ts[tid - off];
    __syncthreads();
    ts[tid] = v;
    __syncthreads();
  }
  float run = tid ? ts[tid - 1] : 0.f;
  float* S = ws + WS_S + b*SSTRIDE;
#pragma unroll
  for (int u = 0; u < 6; ++u) { S[base + u] = run; run += y[u]; }
  if (tid == 255) S[ROWS] = run;
#pragma unroll
  for (int u = 0; u < 6; ++u) S[ROWS + 1 + tid*6 + u] = BIGF;
}

// ---------------- K8a: chunk-partial minima of segment averages --------------
__global__ __launch_bounds__(256) void k8a(float* __restrict__ ws)
{
  const int bi = blockIdx.x;
  const int c = bi & 7, ib = (bi >> 3) % 6, b = bi / 48;
  const int tid = threadIdx.x;
  __shared__ float Sseg[448];
  __shared__ float invl[192];
  const float* S = ws + WS_S + b*SSTRIDE;
  const int ibase = ib*256;
  const int segbase = ibase + c*192 + 1;
  Sseg[tid] = S[segbase + tid];
  if (tid < 192) {
    Sseg[256 + tid] = S[segbase + 256 + tid];
    invl[tid] = 1.0f / (float)(c*192 + tid + 1);
  }
  __syncthreads();
  const int i = ibase + tid;
  const float Si = S[i];
  float gm = 3.0e38f;
#pragma unroll 8
  for (int k = 0; k < 192; ++k)
    gm = fminf(gm, (Sseg[tid + k] - Si) * invl[k]);
  ws[WS_GPART + (b*8 + c)*ROWS + i] = gm;
}

// --------- K8b: reduce partials, prefix-max (isotonic), final ranks ----------
__global__ __launch_bounds__(768) void k8b(float* __restrict__ ws,
                                           float* __restrict__ out)
{
  const int b = blockIdx.x, tid = threadIdx.x;
  __shared__ float g[ROWS];
  __shared__ float pm[768];
  for (int t = tid; t < ROWS; t += 768) {
    float gm = 3.0e38f;
#pragma unroll
    for (int c = 0; c < 8; ++c)
      gm = fminf(gm, ws[WS_GPART + (b*8 + c)*ROWS + t]);
    g[t] = gm;
  }
  __syncthreads();
  const float a = g[2*tid], cc = g[2*tid + 1];
  pm[tid] = fmaxf(a, cc);
  __syncthreads();
  for (int off = 1; off < 768; off <<= 1) {
    float v = pm[tid];
    if (tid >= off) v = fmaxf(v, pm[tid - off]);
    __syncthreads();
    pm[tid] = v;
    __syncthreads();
  }
  const float excl = tid ? pm[tid - 1] : -3.0e38f;
  const float i0 = fmaxf(excl, a);
  const float i1 = fmaxf(i0, cc);
  g[2*tid] = i0; g[2*tid + 1] = i1;
  __syncthreads();
  const float* xs = ws + WS_XS + b*ROWS;
  const int* desc = reinterpret_cast<const int*>(ws) + WS_DESC + b*ROWS;
  for (int t = tid; t < ROWS; t += 768) {
    const int dr = desc[t];
    out[b*ROWS + t] = xs[dr] + g[dr];
  }
}

extern "C" void kernel_launch(void* const* d_in, const int* in_sizes, int n_in,
                              void* d_out, int out_size, void* d_ws, size_t ws_size,
                              hipStream_t stream) {
  const float* table = (const float*)d_in[0];
  const float* w1  = (const float*)d_in[1];
  const float* b1  = (const float*)d_in[2];
  const float* w2  = (const float*)d_in[3];
  const float* b2  = (const float*)d_in[4];
  const float* mw  = (const float*)d_in[5];
  const float* mb  = (const float*)d_in[6];
  const float* dw1 = (const float*)d_in[7];
  const float* db1 = (const float*)d_in[8];
  const float* dw2 = (const float*)d_in[9];
  const float* db2 = (const float*)d_in[10];
  const int* labels = (const int*)d_in[11];
  const int* bsp    = (const int*)d_in[12];
  float* out = (float*)d_out;
  float* ws  = (float*)d_ws;

  k1_ae<<<192, 256, 0, stream>>>(table, w1, b1, w2, b2, mw, mb, dw1, db1, dw2, db2, labels, ws);
  k345<<<8, 256, 0, stream>>>(labels, ws, out);
  k6_count<<<192, 256, 0, stream>>>(ws, out);
  k67<<<8, 256, 0, stream>>>(bsp, ws, out);
  k8a<<<384, 256, 0, stream>>>(ws);
  k8b<<<8, 768, 0, stream>>>(ws, out);
}